// Round 7
// baseline (698.718 us; speedup 1.0000x reference)
//
#include <hip/hip_runtime.h>
#include <hip/hip_bf16.h>

#define NF 40960
#define MD 256
#define BATCH 2048
#define CAP 512            // fallback path capacity
#define CAPB 128           // per-row index capacity (lambda=32, huge margin)
#define NTILE ((NF / 64) * (MD / 64))   // fallback transpose tiles
#define NROWS (2 * BATCH)

typedef float vf4 __attribute__((ext_vector_type(4)));
typedef unsigned int vu4 __attribute__((ext_vector_type(4)));

__device__ __forceinline__ float clip01(float v) {
    return fminf(fmaxf(v, 0.0f), 1.0f);
}

// ===========================================================================
// Kernel 1: transpose ft_w (M x F -> F x M), full-column 256x64 tiles.
// Reads 256B segments, writes 64KB fully contiguous per block. Writes the
// zero pad row (index NF). Must complete before nnue_fused (ftT dependency).
// ===========================================================================
__global__ __launch_bounds__(256, 2) void transpose_ft2(
    const float* __restrict__ in, float* __restrict__ outT)
{
    __shared__ float tile[256][65];
    const int b = blockIdx.x;
    const int t = threadIdx.x;
    const int f0 = b * 64;
    if (b == 0) outT[(size_t)NF * MD + t] = 0.0f;   // zero pad row

    const int tx = t & 63;
    const int ty = t >> 6;
    #pragma unroll 8
    for (int r = ty; r < 256; r += 4)
        tile[r][tx] = in[(size_t)r * NF + f0 + tx];
    __syncthreads();
    #pragma unroll 8
    for (int r = 0; r < 64; ++r)
        outT[(size_t)(f0 + r) * MD + t] = tile[t][r];
}

// ===========================================================================
// Kernel 2 (fused): per-position scan (both colors) + gather + MLP.
// - Mask build: 80 branch-free NT uint4 loads (40/color). NT = minimal
//   L2/L3 allocation so the 671MB stream does NOT evict ftT (42MB) from
//   MALL -> gather reads stay L3-hits (R4/R5 showed gather ~310us when
//   ftT was evicted vs ~150us when fresh).
// - Indices stay in LDS (no global idx round-trip, one fewer launch).
// - Gather+MLP: verbatim verified code, lists padded to mult-of-8 with
//   dummy index NF -> zero pad row.
// ===========================================================================
struct FSmem {
    int iw[CAPB + 8], ib[CAPB + 8];
    int nw, nb;
    float xsh[512];
    float red[32][9];
    float ysh[32], zsh[32];
};

__global__ __launch_bounds__(256, 4) void nnue_fused(
    const float* __restrict__ wf, const float* __restrict__ bfeat,
    const float* __restrict__ ftT,
    const float* __restrict__ ft_b, const float* __restrict__ stm,
    const float* __restrict__ l1_w, const float* __restrict__ l1_b,
    const float* __restrict__ l2_w, const float* __restrict__ l2_b,
    const float* __restrict__ l3_w, const float* __restrict__ l3_b,
    float* __restrict__ out)
{
    __shared__ FSmem s;
    const int pos = blockIdx.x;
    const int t = threadIdx.x;
    if (t == 0) { s.nw = 0; s.nb = 0; }
    __syncthreads();

    const vu4* srcW = (const vu4*)(wf + (size_t)pos * NF);
    const vu4* srcB = (const vu4*)(bfeat + (size_t)pos * NF);

    // ---- branch-free mask build, both colors (bit29 of 0x3F800000 == 1)
    unsigned int mw[5], mb[5];
    #pragma unroll
    for (int w = 0; w < 5; ++w) {
        unsigned int aW = 0, aB = 0;
        #pragma unroll
        for (int q = 0; q < 8; ++q) {
            vu4 v = __builtin_nontemporal_load(srcW + t + (w * 8 + q) * 256);
            aW |= (((v.x >> 29) & 1u)
                 | (((v.y >> 29) & 1u) << 1)
                 | (((v.z >> 29) & 1u) << 2)
                 | (((v.w >> 29) & 1u) << 3)) << (4 * q);
        }
        #pragma unroll
        for (int q = 0; q < 8; ++q) {
            vu4 v = __builtin_nontemporal_load(srcB + t + (w * 8 + q) * 256);
            aB |= (((v.x >> 29) & 1u)
                 | (((v.y >> 29) & 1u) << 1)
                 | (((v.z >> 29) & 1u) << 2)
                 | (((v.w >> 29) & 1u) << 3)) << (4 * q);
        }
        mw[w] = aW; mb[w] = aB;
    }

    // ---- sparse emit into LDS (rare path, ~12% of threads per color)
    if (mw[0] | mw[1] | mw[2] | mw[3] | mw[4]) {
        #pragma unroll
        for (int w = 0; w < 5; ++w) {
            unsigned int x = mw[w];
            while (x) {
                const int b = __builtin_ctz(x);
                x &= x - 1;
                const int k = w * 8 + (b >> 2);
                const int fi = 4 * (t + k * 256) + (b & 3);
                const int p = atomicAdd(&s.nw, 1);
                if (p < CAPB) s.iw[p] = fi;
            }
        }
    }
    if (mb[0] | mb[1] | mb[2] | mb[3] | mb[4]) {
        #pragma unroll
        for (int w = 0; w < 5; ++w) {
            unsigned int x = mb[w];
            while (x) {
                const int b = __builtin_ctz(x);
                x &= x - 1;
                const int k = w * 8 + (b >> 2);
                const int fi = 4 * (t + k * 256) + (b & 3);
                const int p = atomicAdd(&s.nb, 1);
                if (p < CAPB) s.ib[p] = fi;
            }
        }
    }
    __syncthreads();

    // ---- pad lists to common multiple-of-8 (dummy -> zero row NF)
    const int cw = min(s.nw, CAPB);
    const int cb = min(s.nb, CAPB);
    const int m = (max(cw, cb) + 7) & ~7;
    for (int j = cw + t; j < m; j += 256) s.iw[j] = NF;
    for (int j = cb + t; j < m; j += 256) s.ib[j] = NF;
    __syncthreads();

    // ---- batched gather: 16 independent loads per iteration (verified)
    const float bias = ft_b[t];
    float aw = 0.0f, ab = 0.0f;
    for (int j = 0; j < m; j += 8) {
        float vw[8], vb[8];
        #pragma unroll
        for (int q = 0; q < 8; ++q) vw[q] = ftT[(size_t)s.iw[j + q] * MD + t];
        #pragma unroll
        for (int q = 0; q < 8; ++q) vb[q] = ftT[(size_t)s.ib[j + q] * MD + t];
        aw += ((vw[0] + vw[1]) + (vw[2] + vw[3])) + ((vw[4] + vw[5]) + (vw[6] + vw[7]));
        ab += ((vb[0] + vb[1]) + (vb[2] + vb[3])) + ((vb[4] + vb[5]) + (vb[6] + vb[7]));
    }
    const float accW = bias + aw;
    const float accB = bias + ab;

    // ---- verified MLP tail
    const float sv = stm[pos];
    s.xsh[t]       = clip01(sv * accW + (1.0f - sv) * accB);
    s.xsh[256 + t] = clip01(sv * accB + (1.0f - sv) * accW);
    __syncthreads();
    {   // L1: n = t&31 (broadcast reads), chunk c = t>>5
        const int n = t & 31;
        const int c = t >> 5;
        const float* w1 = l1_w + (size_t)n * 512 + c * 64;
        const float* xx = s.xsh + c * 64;
        float p = 0.0f;
        #pragma unroll
        for (int j = 0; j < 64; ++j) p += xx[j] * w1[j];
        s.red[n][c] = p;
    }
    __syncthreads();
    if (t < 32) {
        float v = l1_b[t];
        #pragma unroll
        for (int c = 0; c < 8; ++c) v += s.red[t][c];
        s.ysh[t] = clip01(v);
    }
    __syncthreads();
    if (t < 32) {
        float v = l2_b[t];
        const float* w2 = l2_w + t * 32;
        #pragma unroll
        for (int j = 0; j < 32; ++j) v += s.ysh[j] * w2[j];
        s.zsh[t] = clip01(v);
    }
    __syncthreads();
    if (t == 0) {
        float v = l3_b[0];
        #pragma unroll
        for (int j = 0; j < 32; ++j) v += s.zsh[j] * l3_w[j];
        out[pos] = (clip01(v) - 0.5f) * 20000.0f;
    }
}

// ===========================================================================
// Fallback path (verified R1): separate transpose + monolithic kernel.
// ===========================================================================
__global__ __launch_bounds__(256) void transpose_ft(const float* __restrict__ in,
                                                    float* __restrict__ outT) {
    __shared__ float tile[64][65];
    const int b = blockIdx.x;
    const int t = threadIdx.x;
    const int f0 = (b % (NF / 64)) * 64;
    const int m0 = (b / (NF / 64)) * 64;
    const int tx = t & 63;
    const int ty = t >> 6;
    #pragma unroll
    for (int r = ty; r < 64; r += 4)
        tile[r][tx] = in[(size_t)(m0 + r) * NF + f0 + tx];
    __syncthreads();
    #pragma unroll
    for (int r = ty; r < 64; r += 4)
        outT[(size_t)(f0 + r) * MD + m0 + tx] = tile[tx][r];
}

struct ScanSmem {
    int idxW[CAP], idxB[CAP];
    int nW, nB;
    float xsh[512];
    float red[32][9];
    float ysh[32], zsh[32];
};
union Smem {
    float tile[64][65];
    ScanSmem s;
};

__device__ __forceinline__ void scan_pos(ScanSmem& s, int t, int pos,
    const float* __restrict__ wf, const float* __restrict__ bfeat)
{
    if (t == 0) { s.nW = 0; s.nB = 0; }
    __syncthreads();
    const vf4* wf4 = (const vf4*)(wf + (size_t)pos * NF);
    const vf4* bf4 = (const vf4*)(bfeat + (size_t)pos * NF);
    #pragma unroll 4
    for (int i = t; i < NF / 4; i += 256) {
        vf4 v = wf4[i];
        if (v.x + v.y + v.z + v.w != 0.0f) {
            if (v.x != 0.0f) { int p = atomicAdd(&s.nW, 1); if (p < CAP) s.idxW[p] = 4 * i;     }
            if (v.y != 0.0f) { int p = atomicAdd(&s.nW, 1); if (p < CAP) s.idxW[p] = 4 * i + 1; }
            if (v.z != 0.0f) { int p = atomicAdd(&s.nW, 1); if (p < CAP) s.idxW[p] = 4 * i + 2; }
            if (v.w != 0.0f) { int p = atomicAdd(&s.nW, 1); if (p < CAP) s.idxW[p] = 4 * i + 3; }
        }
        vf4 uu = bf4[i];
        if (uu.x + uu.y + uu.z + uu.w != 0.0f) {
            if (uu.x != 0.0f) { int p = atomicAdd(&s.nB, 1); if (p < CAP) s.idxB[p] = 4 * i;     }
            if (uu.y != 0.0f) { int p = atomicAdd(&s.nB, 1); if (p < CAP) s.idxB[p] = 4 * i + 1; }
            if (uu.z != 0.0f) { int p = atomicAdd(&s.nB, 1); if (p < CAP) s.idxB[p] = 4 * i + 2; }
            if (uu.w != 0.0f) { int p = atomicAdd(&s.nB, 1); if (p < CAP) s.idxB[p] = 4 * i + 3; }
        }
    }
    __syncthreads();
}

__device__ __forceinline__ void gather_tail(ScanSmem& s, int t, int pos,
    const float* __restrict__ gt, int transposed,
    const float* __restrict__ ft_b, const float* __restrict__ stm,
    const float* __restrict__ l1_w, const float* __restrict__ l1_b,
    const float* __restrict__ l2_w, const float* __restrict__ l2_b,
    const float* __restrict__ l3_w, const float* __restrict__ l3_b,
    float* __restrict__ out)
{
    const int cw = min(s.nW, CAP);
    const int cb = min(s.nB, CAP);

    float accW = ft_b[t];
    float accB = ft_b[t];
    if (transposed) {
        for (int j = 0; j < cw; ++j) accW += gt[(size_t)s.idxW[j] * MD + t];
        for (int j = 0; j < cb; ++j) accB += gt[(size_t)s.idxB[j] * MD + t];
    } else {
        const float* row = gt + (size_t)t * NF;
        for (int j = 0; j < cw; ++j) accW += row[s.idxW[j]];
        for (int j = 0; j < cb; ++j) accB += row[s.idxB[j]];
    }

    const float sv = stm[pos];
    s.xsh[t]       = clip01(sv * accW + (1.0f - sv) * accB);
    s.xsh[256 + t] = clip01(sv * accB + (1.0f - sv) * accW);
    __syncthreads();

    {
        const int n = t & 31;
        const int c = t >> 5;
        const float* w1 = l1_w + (size_t)n * 512 + c * 64;
        const float* xx = s.xsh + c * 64;
        float p = 0.0f;
        #pragma unroll
        for (int j = 0; j < 64; ++j) p += xx[j] * w1[j];
        s.red[n][c] = p;
    }
    __syncthreads();
    if (t < 32) {
        float v = l1_b[t];
        #pragma unroll
        for (int c = 0; c < 8; ++c) v += s.red[t][c];
        s.ysh[t] = clip01(v);
    }
    __syncthreads();
    if (t < 32) {
        float v = l2_b[t];
        const float* w2 = l2_w + t * 32;
        #pragma unroll
        for (int j = 0; j < 32; ++j) v += s.ysh[j] * w2[j];
        s.zsh[t] = clip01(v);
    }
    __syncthreads();
    if (t == 0) {
        float v = l3_b[0];
        #pragma unroll
        for (int j = 0; j < 32; ++j) v += s.zsh[j] * l3_w[j];
        out[pos] = (clip01(v) - 0.5f) * 20000.0f;
    }
}

__global__ __launch_bounds__(256) void nnue_plain(
    const float* __restrict__ wf, const float* __restrict__ bfeat,
    const float* __restrict__ stm, const float* __restrict__ gt,
    const float* __restrict__ ft_b,
    const float* __restrict__ l1_w, const float* __restrict__ l1_b,
    const float* __restrict__ l2_w, const float* __restrict__ l2_b,
    const float* __restrict__ l3_w, const float* __restrict__ l3_b,
    float* __restrict__ out, int transposed)
{
    __shared__ Smem u;
    const int pos = blockIdx.x;
    const int t = threadIdx.x;
    scan_pos(u.s, t, pos, wf, bfeat);
    gather_tail(u.s, t, pos, gt, transposed, ft_b, stm,
                l1_w, l1_b, l2_w, l2_b, l3_w, l3_b, out);
}

extern "C" void kernel_launch(void* const* d_in, const int* in_sizes, int n_in,
                              void* d_out, int out_size, void* d_ws, size_t ws_size,
                              hipStream_t stream) {
    const float* wf    = (const float*)d_in[0];
    const float* bfeat = (const float*)d_in[1];
    const float* stm   = (const float*)d_in[2];
    const float* ft_w  = (const float*)d_in[3];
    const float* ft_b  = (const float*)d_in[4];
    const float* l1_w  = (const float*)d_in[5];
    const float* l1_b  = (const float*)d_in[6];
    const float* l2_w  = (const float*)d_in[7];
    const float* l2_b  = (const float*)d_in[8];
    const float* l3_w  = (const float*)d_in[9];
    const float* l3_b  = (const float*)d_in[10];
    float* out = (float*)d_out;

    float* ftT = (float*)d_ws;
    const size_t needFull = (size_t)(NF + 1) * MD * sizeof(float);  // ftT + pad row
    const size_t needT    = (size_t)NF * MD * sizeof(float);

    if (ws_size >= needFull) {
        // fast path: transpose, then fused scan+gather+MLP (2 dispatches)
        transpose_ft2<<<NF / 64, 256, 0, stream>>>(ft_w, ftT);
        nnue_fused<<<BATCH, 256, 0, stream>>>(
            wf, bfeat, ftT, ft_b, stm,
            l1_w, l1_b, l2_w, l2_b, l3_w, l3_b, out);
        return;
    }

    // fallback: verified two-kernel path
    if (ws_size >= needT) {
        transpose_ft<<<NTILE, 256, 0, stream>>>(ft_w, ftT);
        nnue_plain<<<BATCH, 256, 0, stream>>>(
            wf, bfeat, stm, ftT, ft_b,
            l1_w, l1_b, l2_w, l2_b, l3_w, l3_b, out, 1);
    } else {
        nnue_plain<<<BATCH, 256, 0, stream>>>(
            wf, bfeat, stm, ft_w, ft_b,
            l1_w, l1_b, l2_w, l2_b, l3_w, l3_b, out, 0);
    }
}

// Round 8
// 658.266 us; speedup vs baseline: 1.0615x; 1.0615x over previous
//
#include <hip/hip_runtime.h>
#include <hip/hip_bf16.h>

#define NF 40960
#define MD 256
#define BATCH 2048
#define CAP 512            // fallback path capacity
#define CAPB 128           // per-row index capacity (lambda=32, huge margin)
#define NTILE ((NF / 64) * (MD / 64))   // 2560 64x64 tiles
#define NROWS (2 * BATCH)               // 4096 (pos,color) rows

typedef float vf4 __attribute__((ext_vector_type(4)));
typedef unsigned int vu4 __attribute__((ext_vector_type(4)));

__device__ __forceinline__ float clip01(float v) {
    return fminf(fmaxf(v, 0.0f), 1.0f);
}

// ===========================================================================
// Kernel 1: branch-free streaming scan (R3-verified: NT loads, bounds(,4)).
// Block g scans one contiguous 160KB row: color=g>>11, pos=g&2047.
// Measured 3.44-3.55 TB/s across every variant tried (NT/plain/occupancy/
// ILP) == the chip's demonstrated pure-read rate (m13 6.29 TB/s is a COPY,
// read component ~3.2). This is the read roofline for the compulsory 672MB.
// ===========================================================================
__global__ __launch_bounds__(256, 4) void nnue_scan(
    const float* __restrict__ wf, const float* __restrict__ bfeat,
    int* __restrict__ cnt, int* __restrict__ idxg)
{
    __shared__ int lidx[CAPB];
    __shared__ int lcnt;
    const int g = blockIdx.x;
    const int t = threadIdx.x;
    const int pos = g & (BATCH - 1);
    const int color = g >> 11;

    if (t == 0) lcnt = 0;
    __syncthreads();

    const vu4* src = (const vu4*)((color ? bfeat : wf) + (size_t)pos * NF);

    // ---- branch-free mask build: 40 NT uint4 loads -> 5 mask words.
    // bit29 of 0x3F800000 distinguishes 1.0f from 0.0f.
    unsigned int mask[5];
    #pragma unroll
    for (int w = 0; w < 5; ++w) {
        unsigned int acc = 0;
        #pragma unroll
        for (int q = 0; q < 8; ++q) {
            vu4 v = __builtin_nontemporal_load(src + t + (w * 8 + q) * 256);
            unsigned int nib = ((v.x >> 29) & 1u)
                             | (((v.y >> 29) & 1u) << 1)
                             | (((v.z >> 29) & 1u) << 2)
                             | (((v.w >> 29) & 1u) << 3);
            acc |= nib << (4 * q);
        }
        mask[w] = acc;
    }

    // ---- sparse emit (~12% of threads non-empty)
    if (mask[0] | mask[1] | mask[2] | mask[3] | mask[4]) {
        #pragma unroll
        for (int w = 0; w < 5; ++w) {
            unsigned int x = mask[w];
            while (x) {
                const int b = __builtin_ctz(x);
                x &= x - 1;
                const int k = w * 8 + (b >> 2);       // which load
                const int fi = 4 * (t + k * 256) + (b & 3);
                const int p = atomicAdd(&lcnt, 1);
                if (p < CAPB) lidx[p] = fi;
            }
        }
    }
    __syncthreads();

    // ---- coalesced flush (no global atomics)
    const int n = min(lcnt, CAPB);
    for (int j = t; j < n; j += 256) idxg[(size_t)g * CAPB + j] = lidx[j];
    if (t == 0) cnt[g] = n;
}

// ===========================================================================
// Kernel 2: transpose ft_w (M x F -> F x M), 64x64 tiles, 2560 blocks
// (R3-verified variant) + zero pad row. Runs AFTER the scan so ftT is
// freshly L3-resident when the gather consumes it (nothing big streams
// in between).
// ===========================================================================
__global__ __launch_bounds__(256) void transpose_ft_fast(
    const float* __restrict__ in, float* __restrict__ outT)
{
    __shared__ float tile[64][65];
    const int b = blockIdx.x;
    const int t = threadIdx.x;
    if (b == 0) outT[(size_t)NF * MD + t] = 0.0f;   // zero pad row (index NF)
    const int f0 = (b % (NF / 64)) * 64;
    const int m0 = (b / (NF / 64)) * 64;
    const int tx = t & 63;
    const int ty = t >> 6;
    #pragma unroll
    for (int r = ty; r < 64; r += 4)
        tile[r][tx] = in[(size_t)(m0 + r) * NF + f0 + tx];
    __syncthreads();
    #pragma unroll
    for (int r = ty; r < 64; r += 4)
        outT[(size_t)(f0 + r) * MD + m0 + tx] = tile[tx][r];
}

// ===========================================================================
// Kernel 3: batched gather from ftT (L3-fresh) + MLP tail (verified).
// Lists padded to multiple of 8 with dummy index NF -> zero pad row, so the
// gather loop is mask-free with 16 independent loads in flight.
// ===========================================================================
struct GSmem {
    int iw[CAPB + 8], ib[CAPB + 8];
    float xsh[512];
    float red[32][9];
    float ysh[32], zsh[32];
};

__global__ __launch_bounds__(256, 4) void nnue_gather(
    const float* __restrict__ ftT,
    const int* __restrict__ cnt, const int* __restrict__ idxg,
    const float* __restrict__ ft_b, const float* __restrict__ stm,
    const float* __restrict__ l1_w, const float* __restrict__ l1_b,
    const float* __restrict__ l2_w, const float* __restrict__ l2_b,
    const float* __restrict__ l3_w, const float* __restrict__ l3_b,
    float* __restrict__ out)
{
    __shared__ GSmem s;
    const int pos = blockIdx.x;
    const int t = threadIdx.x;

    const int cw = min(cnt[pos], CAPB);
    const int cb = min(cnt[BATCH + pos], CAPB);
    const int m = (max(cw, cb) + 7) & ~7;

    for (int j = t; j < cw; j += 256) s.iw[j] = idxg[(size_t)pos * CAPB + j];
    for (int j = t; j < cb; j += 256) s.ib[j] = idxg[(size_t)(BATCH + pos) * CAPB + j];
    for (int j = cw + t; j < m; j += 256) s.iw[j] = NF;   // pad -> zero row
    for (int j = cb + t; j < m; j += 256) s.ib[j] = NF;
    __syncthreads();

    // ---- batched gather: 16 independent loads per iteration
    const float bias = ft_b[t];
    float aw = 0.0f, ab = 0.0f;
    for (int j = 0; j < m; j += 8) {
        float vw[8], vb[8];
        #pragma unroll
        for (int q = 0; q < 8; ++q) vw[q] = ftT[(size_t)s.iw[j + q] * MD + t];
        #pragma unroll
        for (int q = 0; q < 8; ++q) vb[q] = ftT[(size_t)s.ib[j + q] * MD + t];
        aw += ((vw[0] + vw[1]) + (vw[2] + vw[3])) + ((vw[4] + vw[5]) + (vw[6] + vw[7]));
        ab += ((vb[0] + vb[1]) + (vb[2] + vb[3])) + ((vb[4] + vb[5]) + (vb[6] + vb[7]));
    }
    const float accW = bias + aw;
    const float accB = bias + ab;

    // ---- verified MLP tail
    const float sv = stm[pos];
    s.xsh[t]       = clip01(sv * accW + (1.0f - sv) * accB);
    s.xsh[256 + t] = clip01(sv * accB + (1.0f - sv) * accW);
    __syncthreads();
    {   // L1: n = t&31 (broadcast reads), chunk c = t>>5
        const int n = t & 31;
        const int c = t >> 5;
        const float* w1 = l1_w + (size_t)n * 512 + c * 64;
        const float* xx = s.xsh + c * 64;
        float p = 0.0f;
        #pragma unroll
        for (int j = 0; j < 64; ++j) p += xx[j] * w1[j];
        s.red[n][c] = p;
    }
    __syncthreads();
    if (t < 32) {
        float v = l1_b[t];
        #pragma unroll
        for (int c = 0; c < 8; ++c) v += s.red[t][c];
        s.ysh[t] = clip01(v);
    }
    __syncthreads();
    if (t < 32) {
        float v = l2_b[t];
        const float* w2 = l2_w + t * 32;
        #pragma unroll
        for (int j = 0; j < 32; ++j) v += s.ysh[j] * w2[j];
        s.zsh[t] = clip01(v);
    }
    __syncthreads();
    if (t == 0) {
        float v = l3_b[0];
        #pragma unroll
        for (int j = 0; j < 32; ++j) v += s.zsh[j] * l3_w[j];
        out[pos] = (clip01(v) - 0.5f) * 20000.0f;
    }
}

// ===========================================================================
// Fallback path (verified R1): separate transpose + monolithic kernel.
// ===========================================================================
__global__ __launch_bounds__(256) void transpose_ft(const float* __restrict__ in,
                                                    float* __restrict__ outT) {
    __shared__ float tile[64][65];
    const int b = blockIdx.x;
    const int t = threadIdx.x;
    const int f0 = (b % (NF / 64)) * 64;
    const int m0 = (b / (NF / 64)) * 64;
    const int tx = t & 63;
    const int ty = t >> 6;
    #pragma unroll
    for (int r = ty; r < 64; r += 4)
        tile[r][tx] = in[(size_t)(m0 + r) * NF + f0 + tx];
    __syncthreads();
    #pragma unroll
    for (int r = ty; r < 64; r += 4)
        outT[(size_t)(f0 + r) * MD + m0 + tx] = tile[tx][r];
}

struct ScanSmem {
    int idxW[CAP], idxB[CAP];
    int nW, nB;
    float xsh[512];
    float red[32][9];
    float ysh[32], zsh[32];
};
union Smem {
    float tile[64][65];
    ScanSmem s;
};

__device__ __forceinline__ void scan_pos(ScanSmem& s, int t, int pos,
    const float* __restrict__ wf, const float* __restrict__ bfeat)
{
    if (t == 0) { s.nW = 0; s.nB = 0; }
    __syncthreads();
    const vf4* wf4 = (const vf4*)(wf + (size_t)pos * NF);
    const vf4* bf4 = (const vf4*)(bfeat + (size_t)pos * NF);
    #pragma unroll 4
    for (int i = t; i < NF / 4; i += 256) {
        vf4 v = wf4[i];
        if (v.x + v.y + v.z + v.w != 0.0f) {
            if (v.x != 0.0f) { int p = atomicAdd(&s.nW, 1); if (p < CAP) s.idxW[p] = 4 * i;     }
            if (v.y != 0.0f) { int p = atomicAdd(&s.nW, 1); if (p < CAP) s.idxW[p] = 4 * i + 1; }
            if (v.z != 0.0f) { int p = atomicAdd(&s.nW, 1); if (p < CAP) s.idxW[p] = 4 * i + 2; }
            if (v.w != 0.0f) { int p = atomicAdd(&s.nW, 1); if (p < CAP) s.idxW[p] = 4 * i + 3; }
        }
        vf4 uu = bf4[i];
        if (uu.x + uu.y + uu.z + uu.w != 0.0f) {
            if (uu.x != 0.0f) { int p = atomicAdd(&s.nB, 1); if (p < CAP) s.idxB[p] = 4 * i;     }
            if (uu.y != 0.0f) { int p = atomicAdd(&s.nB, 1); if (p < CAP) s.idxB[p] = 4 * i + 1; }
            if (uu.z != 0.0f) { int p = atomicAdd(&s.nB, 1); if (p < CAP) s.idxB[p] = 4 * i + 2; }
            if (uu.w != 0.0f) { int p = atomicAdd(&s.nB, 1); if (p < CAP) s.idxB[p] = 4 * i + 3; }
        }
    }
    __syncthreads();
}

__device__ __forceinline__ void gather_tail(ScanSmem& s, int t, int pos,
    const float* __restrict__ gt, int transposed,
    const float* __restrict__ ft_b, const float* __restrict__ stm,
    const float* __restrict__ l1_w, const float* __restrict__ l1_b,
    const float* __restrict__ l2_w, const float* __restrict__ l2_b,
    const float* __restrict__ l3_w, const float* __restrict__ l3_b,
    float* __restrict__ out)
{
    const int cw = min(s.nW, CAP);
    const int cb = min(s.nB, CAP);

    float accW = ft_b[t];
    float accB = ft_b[t];
    if (transposed) {
        for (int j = 0; j < cw; ++j) accW += gt[(size_t)s.idxW[j] * MD + t];
        for (int j = 0; j < cb; ++j) accB += gt[(size_t)s.idxB[j] * MD + t];
    } else {
        const float* row = gt + (size_t)t * NF;
        for (int j = 0; j < cw; ++j) accW += row[s.idxW[j]];
        for (int j = 0; j < cb; ++j) accB += row[s.idxB[j]];
    }

    const float sv = stm[pos];
    s.xsh[t]       = clip01(sv * accW + (1.0f - sv) * accB);
    s.xsh[256 + t] = clip01(sv * accB + (1.0f - sv) * accW);
    __syncthreads();

    {
        const int n = t & 31;
        const int c = t >> 5;
        const float* w1 = l1_w + (size_t)n * 512 + c * 64;
        const float* xx = s.xsh + c * 64;
        float p = 0.0f;
        #pragma unroll
        for (int j = 0; j < 64; ++j) p += xx[j] * w1[j];
        s.red[n][c] = p;
    }
    __syncthreads();
    if (t < 32) {
        float v = l1_b[t];
        #pragma unroll
        for (int c = 0; c < 8; ++c) v += s.red[t][c];
        s.ysh[t] = clip01(v);
    }
    __syncthreads();
    if (t < 32) {
        float v = l2_b[t];
        const float* w2 = l2_w + t * 32;
        #pragma unroll
        for (int j = 0; j < 32; ++j) v += s.ysh[j] * w2[j];
        s.zsh[t] = clip01(v);
    }
    __syncthreads();
    if (t == 0) {
        float v = l3_b[0];
        #pragma unroll
        for (int j = 0; j < 32; ++j) v += s.zsh[j] * l3_w[j];
        out[pos] = (clip01(v) - 0.5f) * 20000.0f;
    }
}

__global__ __launch_bounds__(256) void nnue_plain(
    const float* __restrict__ wf, const float* __restrict__ bfeat,
    const float* __restrict__ stm, const float* __restrict__ gt,
    const float* __restrict__ ft_b,
    const float* __restrict__ l1_w, const float* __restrict__ l1_b,
    const float* __restrict__ l2_w, const float* __restrict__ l2_b,
    const float* __restrict__ l3_w, const float* __restrict__ l3_b,
    float* __restrict__ out, int transposed)
{
    __shared__ Smem u;
    const int pos = blockIdx.x;
    const int t = threadIdx.x;
    scan_pos(u.s, t, pos, wf, bfeat);
    gather_tail(u.s, t, pos, gt, transposed, ft_b, stm,
                l1_w, l1_b, l2_w, l2_b, l3_w, l3_b, out);
}

extern "C" void kernel_launch(void* const* d_in, const int* in_sizes, int n_in,
                              void* d_out, int out_size, void* d_ws, size_t ws_size,
                              hipStream_t stream) {
    const float* wf    = (const float*)d_in[0];
    const float* bfeat = (const float*)d_in[1];
    const float* stm   = (const float*)d_in[2];
    const float* ft_w  = (const float*)d_in[3];
    const float* ft_b  = (const float*)d_in[4];
    const float* l1_w  = (const float*)d_in[5];
    const float* l1_b  = (const float*)d_in[6];
    const float* l2_w  = (const float*)d_in[7];
    const float* l2_b  = (const float*)d_in[8];
    const float* l3_w  = (const float*)d_in[9];
    const float* l3_b  = (const float*)d_in[10];
    float* out = (float*)d_out;

    // workspace layout: ftT[(NF+1)*MD] | cnt[NROWS] | idxg[NROWS*CAPB]
    float* ftT = (float*)d_ws;
    int* cnt  = (int*)((float*)d_ws + (size_t)(NF + 1) * MD);
    int* idxg = cnt + NROWS;
    const size_t needFull = (size_t)(NF + 1) * MD * sizeof(float)
                          + (size_t)NROWS * sizeof(int)
                          + (size_t)NROWS * CAPB * sizeof(int);
    const size_t needT = (size_t)NF * MD * sizeof(float);

    if (ws_size >= needFull) {
        // fast path: scan -> transpose -> gather (ftT L3-fresh for gather)
        nnue_scan<<<NROWS, 256, 0, stream>>>(wf, bfeat, cnt, idxg);
        transpose_ft_fast<<<NTILE, 256, 0, stream>>>(ft_w, ftT);
        nnue_gather<<<BATCH, 256, 0, stream>>>(
            ftT, cnt, idxg, ft_b, stm,
            l1_w, l1_b, l2_w, l2_b, l3_w, l3_b, out);
        return;
    }

    // fallback: verified two-kernel path
    if (ws_size >= needT) {
        transpose_ft<<<NTILE, 256, 0, stream>>>(ft_w, ftT);
        nnue_plain<<<BATCH, 256, 0, stream>>>(
            wf, bfeat, stm, ftT, ft_b,
            l1_w, l1_b, l2_w, l2_b, l3_w, l3_b, out, 1);
    } else {
        nnue_plain<<<BATCH, 256, 0, stream>>>(
            wf, bfeat, stm, ft_w, ft_b,
            l1_w, l1_b, l2_w, l2_b, l3_w, l3_b, out, 0);
    }
}